// Round 1
// baseline (1092.102 us; speedup 1.0000x reference)
//
#include <hip/hip_runtime.h>

// Problem constants (fixed by the reference)
constexpr int NN = 100000;          // nodes
constexpr int EE = 1600000;         // edges (without self loops)
constexpr int ET = EE + NN;         // edges + self loops
constexpr float NEG = 0.2f;

// ---------------------------------------------------------------------------
// CSR build: histogram -> scan -> scatter
// ---------------------------------------------------------------------------
__global__ __launch_bounds__(256) void k_count(const int* __restrict__ ei, int* __restrict__ deg) {
    int i = blockIdx.x * 256 + threadIdx.x;
    if (i >= ET) return;
    int dst = (i < EE) ? ei[EE + i] : (i - EE);
    atomicAdd(&deg[dst], 1);
}

__global__ __launch_bounds__(256) void k_part(const int* __restrict__ deg, int* __restrict__ part) {
    __shared__ int sh[256];
    int i = blockIdx.x * 256 + threadIdx.x;
    sh[threadIdx.x] = (i < NN) ? deg[i] : 0;
    __syncthreads();
    for (int o = 128; o; o >>= 1) {
        if (threadIdx.x < o) sh[threadIdx.x] += sh[threadIdx.x + o];
        __syncthreads();
    }
    if (threadIdx.x == 0) part[blockIdx.x] = sh[0];
}

__global__ __launch_bounds__(512) void k_scanp(int* __restrict__ part, int nb) {
    __shared__ int sh[512];
    int t = threadIdx.x;
    int v = (t < nb) ? part[t] : 0;
    sh[t] = v;
    __syncthreads();
    for (int o = 1; o < 512; o <<= 1) {
        int u = (t >= o) ? sh[t - o] : 0;
        __syncthreads();
        sh[t] += u;
        __syncthreads();
    }
    if (t < nb) part[t] = sh[t] - v;   // exclusive
}

__global__ __launch_bounds__(256) void k_scan(const int* __restrict__ deg, const int* __restrict__ part,
                                              int* __restrict__ rs, int* __restrict__ cur) {
    __shared__ int sh[256];
    int t = threadIdx.x;
    int i = blockIdx.x * 256 + t;
    int v = (i < NN) ? deg[i] : 0;
    sh[t] = v;
    __syncthreads();
    for (int o = 1; o < 256; o <<= 1) {
        int u = (t >= o) ? sh[t - o] : 0;
        __syncthreads();
        sh[t] += u;
        __syncthreads();
    }
    int incl = sh[t];
    int base = part[blockIdx.x];
    if (i < NN) {
        rs[i]  = base + incl - v;
        cur[i] = base + incl - v;
        if (i == NN - 1) rs[NN] = base + incl;
    }
}

__global__ __launch_bounds__(256) void k_scatter(const int* __restrict__ ei, int* __restrict__ cur,
                                                 int* __restrict__ csr) {
    int i = blockIdx.x * 256 + threadIdx.x;
    if (i >= ET) return;
    int src, dst;
    if (i < EE) { src = ei[i]; dst = ei[EE + i]; }
    else        { src = i - EE; dst = i - EE; }
    int pos = atomicAdd(&cur[dst], 1);
    csr[pos] = src;
}

// ---------------------------------------------------------------------------
// fp32 GEMM: xp = x @ W.  Block computes ROWS x C tile, thread tile 8x8.
// W tile and transposed x tile staged in LDS; broadcast-heavy LDS reads.
// ---------------------------------------------------------------------------
template <int K, int C, int ROWS>
__global__ __launch_bounds__(256) void gemm_kernel(const float* __restrict__ x, const float* __restrict__ W,
                                                   float* __restrict__ xp, int n) {
    constexpr int KB  = 32;
    constexpr int TCG = C / 8;        // col groups of 8
    constexpr int TRG = 256 / TCG;    // row groups of 8
    static_assert(ROWS == TRG * 8, "tile mismatch");
    __shared__ __align__(16) float xs[KB * ROWS];   // [k][row]
    __shared__ __align__(16) float wsm[KB * C];     // [k][col]

    const int tid = threadIdx.x;
    const int tc  = tid % TCG;
    const int tr  = tid / TCG;
    const long g0 = (long)blockIdx.x * ROWS;

    float acc[8][8];
#pragma unroll
    for (int i = 0; i < 8; i++)
#pragma unroll
        for (int j = 0; j < 8; j++) acc[i][j] = 0.f;

    for (int kb = 0; kb < K; kb += KB) {
        // stage x transposed: xs[k][r]
        for (int idx = tid; idx < ROWS * 8; idx += 256) {
            int r = idx & (ROWS - 1);
            int q = idx / ROWS;          // 0..7 -> k chunk of 4
            long row = g0 + r;
            float4 v = make_float4(0.f, 0.f, 0.f, 0.f);
            if (row < n) v = *(const float4*)(x + row * (long)K + kb + q * 4);
            xs[(q * 4 + 0) * ROWS + r] = v.x;
            xs[(q * 4 + 1) * ROWS + r] = v.y;
            xs[(q * 4 + 2) * ROWS + r] = v.z;
            xs[(q * 4 + 3) * ROWS + r] = v.w;
        }
        // stage W rows kb..kb+KB (contiguous in global)
        for (int idx = tid; idx < KB * C / 4; idx += 256)
            ((float4*)wsm)[idx] = ((const float4*)(W + (long)kb * C))[idx];
        __syncthreads();

#pragma unroll 4
        for (int k = 0; k < KB; k++) {
            float xr[8], wr[8];
            *(float4*)(xr)     = *(const float4*)(xs + k * ROWS + tr * 8);
            *(float4*)(xr + 4) = *(const float4*)(xs + k * ROWS + tr * 8 + 4);
            *(float4*)(wr)     = *(const float4*)(wsm + k * C + tc * 8);
            *(float4*)(wr + 4) = *(const float4*)(wsm + k * C + tc * 8 + 4);
#pragma unroll
            for (int i = 0; i < 8; i++)
#pragma unroll
                for (int j = 0; j < 8; j++) acc[i][j] += xr[i] * wr[j];
        }
        __syncthreads();
    }

#pragma unroll
    for (int i = 0; i < 8; i++) {
        long row = g0 + tr * 8 + i;
        if (row < n) {
            float4 v0 = make_float4(acc[i][0], acc[i][1], acc[i][2], acc[i][3]);
            float4 v1 = make_float4(acc[i][4], acc[i][5], acc[i][6], acc[i][7]);
            *(float4*)(xp + row * (long)C + tc * 8)     = v0;
            *(float4*)(xp + row * (long)C + tc * 8 + 4) = v1;
        }
    }
}

// ---------------------------------------------------------------------------
// attention coefficients: a_src[v,h] = sum_c xp[v,h,c]*att_src[h,c]; same a_dst
// ---------------------------------------------------------------------------
template <int H, int C>
__global__ __launch_bounds__(256) void attn_kernel(const float* __restrict__ xp,
                                                   const float* __restrict__ as_w,
                                                   const float* __restrict__ ad_w,
                                                   float* __restrict__ asrc, float* __restrict__ adst, int n) {
    int idx = blockIdx.x * 256 + threadIdx.x;
    if (idx >= n * H) return;
    int v = idx / H, hh = idx % H;
    constexpr int CH = C / H;
    const float* p  = xp + (long)v * C + hh * CH;
    const float* a1 = as_w + hh * CH;
    const float* a2 = ad_w + hh * CH;
    float s1 = 0.f, s2 = 0.f;
#pragma unroll
    for (int c = 0; c < CH; c += 4) {
        float4 xv = *(const float4*)(p + c);
        float4 w1 = *(const float4*)(a1 + c);
        float4 w2 = *(const float4*)(a2 + c);
        s1 += xv.x * w1.x + xv.y * w1.y + xv.z * w1.z + xv.w * w1.w;
        s2 += xv.x * w2.x + xv.y * w2.y + xv.z * w2.z + xv.w * w2.w;
    }
    asrc[idx] = s1;
    adst[idx] = s2;
}

// ---------------------------------------------------------------------------
// Edge conv: one wave per dst node.
// Phase 1: softmax denominator per head (lane-parallel edges + butterfly).
// Phase 2: lanes split channels; serial over edges, out[v] += alpha*xp[src].
// No segment_max: alpha = exp(e)/sum exp(e) is exact (|e| small here).
// ---------------------------------------------------------------------------
template <int H, int C, bool RELU>
__global__ __launch_bounds__(256) void conv_edge(const int* __restrict__ rs, const int* __restrict__ csr,
                                                 const float* __restrict__ xp,
                                                 const float* __restrict__ asrc, const float* __restrict__ adst,
                                                 const float* __restrict__ bias,
                                                 float* __restrict__ out, int ostride, int ooff) {
    int v = blockIdx.x * 4 + (threadIdx.x >> 6);
    if (v >= NN) return;
    int lane = threadIdx.x & 63;
    int e0 = rs[v], e1 = rs[v + 1];

    float adv[H];
#pragma unroll
    for (int hh = 0; hh < H; hh++) adv[hh] = adst[v * H + hh];

    float dsum[H];
#pragma unroll
    for (int hh = 0; hh < H; hh++) dsum[hh] = 0.f;

    for (int j = e0 + lane; j < e1; j += 64) {
        int s = csr[j];
#pragma unroll
        for (int hh = 0; hh < H; hh++) {
            float e = asrc[s * H + hh] + adv[hh];
            e = (e > 0.f) ? e : NEG * e;
            dsum[hh] += __expf(e);
        }
    }
#pragma unroll
    for (int hh = 0; hh < H; hh++) {
#pragma unroll
        for (int o = 32; o; o >>= 1) dsum[hh] += __shfl_xor(dsum[hh], o, 64);
    }
    float inv[H];
#pragma unroll
    for (int hh = 0; hh < H; hh++) inv[hh] = 1.0f / dsum[hh];

    constexpr int CPL = C / 64;           // channels per lane (2 or 1)
    int c0 = lane * CPL;
    int h0 = c0 / (C / H);                // both channels of a lane share a head
    float acc[CPL];
#pragma unroll
    for (int q = 0; q < CPL; q++) acc[q] = 0.f;

    for (int j = e0; j < e1; ++j) {
        int s = csr[j];
        float e = asrc[s * H + h0] + adv[h0];
        e = (e > 0.f) ? e : NEG * e;
        float a = __expf(e) * inv[h0];
        if constexpr (CPL == 2) {
            float2 xv = *(const float2*)(xp + (long)s * C + c0);
            acc[0] += a * xv.x;
            acc[1] += a * xv.y;
        } else {
            acc[0] += a * xp[(long)s * C + c0];
        }
    }
#pragma unroll
    for (int q = 0; q < CPL; q++) {
        float val = acc[q] + bias[c0 + q];
        if (RELU) val = fmaxf(val, 0.f);
        out[(long)v * ostride + ooff + c0 + q] = val;
    }
}

// ---------------------------------------------------------------------------
// Launch
// ---------------------------------------------------------------------------
extern "C" void kernel_launch(void* const* d_in, const int* in_sizes, int n_in,
                              void* d_out, int out_size, void* d_ws, size_t ws_size,
                              hipStream_t stream) {
    const float* x_ppi = (const float*)d_in[0];
    const float* x_go  = (const float*)d_in[1];
    const int*   ei    = (const int*)d_in[2];
    const float* W1    = (const float*)d_in[3];
    const float* as1   = (const float*)d_in[4];
    const float* ad1   = (const float*)d_in[5];
    const float* b1    = (const float*)d_in[6];
    const float* W2    = (const float*)d_in[7];
    const float* as2   = (const float*)d_in[8];
    const float* ad2   = (const float*)d_in[9];
    const float* b2    = (const float*)d_in[10];
    float* out = (float*)d_out;

    char* ws = (char*)d_ws;
    size_t off = 0;
    auto alloc = [&](size_t bytes) -> void* {
        void* p = ws + off;
        off = (off + bytes + 255) & ~(size_t)255;
        return p;
    };
    int* deg    = (int*)alloc((size_t)NN * 4);
    int* rs     = (int*)alloc((size_t)(NN + 1) * 4);
    int* cur    = (int*)alloc((size_t)NN * 4);
    int* part   = (int*)alloc(512 * 4);
    int* csr    = (int*)alloc((size_t)ET * 4);
    float* xp   = (float*)alloc((size_t)NN * 128 * 4);  // reused by all 3 convs
    float* asr  = (float*)alloc((size_t)NN * 4 * 4);
    float* adsb = (float*)alloc((size_t)NN * 4 * 4);
    float* hbuf = (float*)alloc((size_t)NN * 256 * 4);
    (void)ws_size; (void)in_sizes; (void)n_in; (void)out_size;

    const int NB = (NN + 255) / 256;        // 391
    const int EB = (ET + 255) / 256;        // 6641

    // CSR build (shared by all three convs)
    hipMemsetAsync(deg, 0, (size_t)NN * 4, stream);
    k_count<<<EB, 256, 0, stream>>>(ei, deg);
    k_part<<<NB, 256, 0, stream>>>(deg, part);
    k_scanp<<<1, 512, 0, stream>>>(part, NB);
    k_scan<<<NB, 256, 0, stream>>>(deg, part, rs, cur);
    k_scatter<<<EB, 256, 0, stream>>>(ei, cur, csr);

    // conv1 on x_ppi -> h[:, 0:128]
    gemm_kernel<128, 128, 128><<<(NN + 127) / 128, 256, 0, stream>>>(x_ppi, W1, xp, NN);
    attn_kernel<4, 128><<<(NN * 4 + 255) / 256, 256, 0, stream>>>(xp, as1, ad1, asr, adsb, NN);
    conv_edge<4, 128, true><<<NN / 4, 256, 0, stream>>>(rs, csr, xp, asr, adsb, b1, hbuf, 256, 0);

    // conv1 on x_go -> h[:, 128:256]
    gemm_kernel<128, 128, 128><<<(NN + 127) / 128, 256, 0, stream>>>(x_go, W1, xp, NN);
    attn_kernel<4, 128><<<(NN * 4 + 255) / 256, 256, 0, stream>>>(xp, as1, ad1, asr, adsb, NN);
    conv_edge<4, 128, true><<<NN / 4, 256, 0, stream>>>(rs, csr, xp, asr, adsb, b1, hbuf, 256, 128);

    // conv2 on h -> out
    gemm_kernel<256, 64, 256><<<(NN + 255) / 256, 256, 0, stream>>>(hbuf, W2, xp, NN);
    attn_kernel<1, 64><<<(NN + 255) / 256, 256, 0, stream>>>(xp, as2, ad2, asr, adsb, NN);
    conv_edge<1, 64, false><<<NN / 4, 256, 0, stream>>>(rs, csr, xp, asr, adsb, b2, out, 64, 0);
}

// Round 2
// 897.690 us; speedup vs baseline: 1.2166x; 1.2166x over previous
//
#include <hip/hip_runtime.h>

// Problem constants (fixed by the reference)
constexpr int NN = 100000;          // nodes
constexpr int EE = 1600000;         // edges (without self loops)
constexpr int ET = EE + NN;         // edges + self loops
constexpr float NEG = 0.2f;

// ---------------------------------------------------------------------------
// CSR build: histogram -> scan -> scatter
// ---------------------------------------------------------------------------
__global__ __launch_bounds__(256) void k_count(const int* __restrict__ ei, int* __restrict__ deg) {
    int i = blockIdx.x * 256 + threadIdx.x;
    if (i >= ET) return;
    int dst = (i < EE) ? ei[EE + i] : (i - EE);
    atomicAdd(&deg[dst], 1);
}

__global__ __launch_bounds__(256) void k_part(const int* __restrict__ deg, int* __restrict__ part) {
    __shared__ int sh[256];
    int i = blockIdx.x * 256 + threadIdx.x;
    sh[threadIdx.x] = (i < NN) ? deg[i] : 0;
    __syncthreads();
    for (int o = 128; o; o >>= 1) {
        if (threadIdx.x < o) sh[threadIdx.x] += sh[threadIdx.x + o];
        __syncthreads();
    }
    if (threadIdx.x == 0) part[blockIdx.x] = sh[0];
}

__global__ __launch_bounds__(512) void k_scanp(int* __restrict__ part, int nb) {
    __shared__ int sh[512];
    int t = threadIdx.x;
    int v = (t < nb) ? part[t] : 0;
    sh[t] = v;
    __syncthreads();
    for (int o = 1; o < 512; o <<= 1) {
        int u = (t >= o) ? sh[t - o] : 0;
        __syncthreads();
        sh[t] += u;
        __syncthreads();
    }
    if (t < nb) part[t] = sh[t] - v;   // exclusive
}

__global__ __launch_bounds__(256) void k_scan(const int* __restrict__ deg, const int* __restrict__ part,
                                              int* __restrict__ rs, int* __restrict__ cur) {
    __shared__ int sh[256];
    int t = threadIdx.x;
    int i = blockIdx.x * 256 + t;
    int v = (i < NN) ? deg[i] : 0;
    sh[t] = v;
    __syncthreads();
    for (int o = 1; o < 256; o <<= 1) {
        int u = (t >= o) ? sh[t - o] : 0;
        __syncthreads();
        sh[t] += u;
        __syncthreads();
    }
    int incl = sh[t];
    int base = part[blockIdx.x];
    if (i < NN) {
        rs[i]  = base + incl - v;
        cur[i] = base + incl - v;
        if (i == NN - 1) rs[NN] = base + incl;
    }
}

__global__ __launch_bounds__(256) void k_scatter(const int* __restrict__ ei, int* __restrict__ cur,
                                                 int* __restrict__ csr) {
    int i = blockIdx.x * 256 + threadIdx.x;
    if (i >= ET) return;
    int src, dst;
    if (i < EE) { src = ei[i]; dst = ei[EE + i]; }
    else        { src = i - EE; dst = i - EE; }
    int pos = atomicAdd(&cur[dst], 1);
    csr[pos] = src;
}

// ---------------------------------------------------------------------------
// fp32 GEMM: xp = x @ W.  Block computes ROWS x C tile, thread tile 8x8.
// ---------------------------------------------------------------------------
template <int K, int C, int ROWS>
__global__ __launch_bounds__(256) void gemm_kernel(const float* __restrict__ x, const float* __restrict__ W,
                                                   float* __restrict__ xp, int n) {
    constexpr int KB  = 32;
    constexpr int TCG = C / 8;        // col groups of 8
    constexpr int TRG = 256 / TCG;    // row groups of 8
    static_assert(ROWS == TRG * 8, "tile mismatch");
    __shared__ __align__(16) float xs[KB * ROWS];   // [k][row]
    __shared__ __align__(16) float wsm[KB * C];     // [k][col]

    const int tid = threadIdx.x;
    const int tc  = tid % TCG;
    const int tr  = tid / TCG;
    const long g0 = (long)blockIdx.x * ROWS;

    float acc[8][8];
#pragma unroll
    for (int i = 0; i < 8; i++)
#pragma unroll
        for (int j = 0; j < 8; j++) acc[i][j] = 0.f;

    for (int kb = 0; kb < K; kb += KB) {
        for (int idx = tid; idx < ROWS * 8; idx += 256) {
            int r = idx & (ROWS - 1);
            int q = idx / ROWS;          // 0..7 -> k chunk of 4
            long row = g0 + r;
            float4 v = make_float4(0.f, 0.f, 0.f, 0.f);
            if (row < n) v = *(const float4*)(x + row * (long)K + kb + q * 4);
            xs[(q * 4 + 0) * ROWS + r] = v.x;
            xs[(q * 4 + 1) * ROWS + r] = v.y;
            xs[(q * 4 + 2) * ROWS + r] = v.z;
            xs[(q * 4 + 3) * ROWS + r] = v.w;
        }
        for (int idx = tid; idx < KB * C / 4; idx += 256)
            ((float4*)wsm)[idx] = ((const float4*)(W + (long)kb * C))[idx];
        __syncthreads();

#pragma unroll 4
        for (int k = 0; k < KB; k++) {
            float xr[8], wr[8];
            *(float4*)(xr)     = *(const float4*)(xs + k * ROWS + tr * 8);
            *(float4*)(xr + 4) = *(const float4*)(xs + k * ROWS + tr * 8 + 4);
            *(float4*)(wr)     = *(const float4*)(wsm + k * C + tc * 8);
            *(float4*)(wr + 4) = *(const float4*)(wsm + k * C + tc * 8 + 4);
#pragma unroll
            for (int i = 0; i < 8; i++)
#pragma unroll
                for (int j = 0; j < 8; j++) acc[i][j] += xr[i] * wr[j];
        }
        __syncthreads();
    }

#pragma unroll
    for (int i = 0; i < 8; i++) {
        long row = g0 + tr * 8 + i;
        if (row < n) {
            float4 v0 = make_float4(acc[i][0], acc[i][1], acc[i][2], acc[i][3]);
            float4 v1 = make_float4(acc[i][4], acc[i][5], acc[i][6], acc[i][7]);
            *(float4*)(xp + row * (long)C + tc * 8)     = v0;
            *(float4*)(xp + row * (long)C + tc * 8 + 4) = v1;
        }
    }
}

// ---------------------------------------------------------------------------
// Fused attention coefficients for conv1 (both feature sets, packed float2).
// att_s[v*4+h] = { <xp_ppi[v,h,:],as1[h,:]>, <xp_go[v,h,:],as1[h,:]> }
// ---------------------------------------------------------------------------
__global__ __launch_bounds__(256) void attn1_fused(const float* __restrict__ xpp, const float* __restrict__ xpg,
                                                   const float* __restrict__ as_w, const float* __restrict__ ad_w,
                                                   float2* __restrict__ att_s, float2* __restrict__ att_d, int n) {
    int idx = blockIdx.x * 256 + threadIdx.x;
    if (idx >= n * 4) return;
    int v = idx >> 2, hh = idx & 3;
    const float* pp = xpp + (long)v * 128 + hh * 32;
    const float* pg = xpg + (long)v * 128 + hh * 32;
    const float* a1 = as_w + hh * 32;
    const float* a2 = ad_w + hh * 32;
    float sp1 = 0.f, sp2 = 0.f, sg1 = 0.f, sg2 = 0.f;
#pragma unroll
    for (int c = 0; c < 32; c += 4) {
        float4 xv = *(const float4*)(pp + c);
        float4 yv = *(const float4*)(pg + c);
        float4 w1 = *(const float4*)(a1 + c);
        float4 w2 = *(const float4*)(a2 + c);
        sp1 += xv.x * w1.x + xv.y * w1.y + xv.z * w1.z + xv.w * w1.w;
        sp2 += xv.x * w2.x + xv.y * w2.y + xv.z * w2.z + xv.w * w2.w;
        sg1 += yv.x * w1.x + yv.y * w1.y + yv.z * w1.z + yv.w * w1.w;
        sg2 += yv.x * w2.x + yv.y * w2.y + yv.z * w2.z + yv.w * w2.w;
    }
    att_s[idx] = make_float2(sp1, sg1);
    att_d[idx] = make_float2(sp2, sg2);
}

// attention for conv2 (H=1, C=64)
__global__ __launch_bounds__(256) void attn2_kernel(const float* __restrict__ xp,
                                                    const float* __restrict__ as_w, const float* __restrict__ ad_w,
                                                    float* __restrict__ asrc, float* __restrict__ adst, int n) {
    int v = blockIdx.x * 256 + threadIdx.x;
    if (v >= n) return;
    const float* p = xp + (long)v * 64;
    float s1 = 0.f, s2 = 0.f;
#pragma unroll
    for (int c = 0; c < 64; c += 4) {
        float4 xv = *(const float4*)(p + c);
        float4 w1 = *(const float4*)(as_w + c);
        float4 w2 = *(const float4*)(ad_w + c);
        s1 += xv.x * w1.x + xv.y * w1.y + xv.z * w1.z + xv.w * w1.w;
        s2 += xv.x * w2.x + xv.y * w2.y + xv.z * w2.z + xv.w * w2.w;
    }
    asrc[v] = s1;
    adst[v] = s2;
}

// ---------------------------------------------------------------------------
// Fused single-pass conv1 edge kernel (both feature sets, H=4, C=128).
// One wave per dst node; lanes carry 2 channels of each set. Unnormalized
// softmax accumulated in-line (no max-subtraction needed: |e| ~ O(1)); one
// divide at the end. 2x unrolled: 4 independent row gathers in flight.
// ---------------------------------------------------------------------------
__global__ __launch_bounds__(256) void conv1_edge_fused(const int* __restrict__ rs, const int* __restrict__ csr,
                                                        const float* __restrict__ xpp, const float* __restrict__ xpg,
                                                        const float2* __restrict__ att_s, const float2* __restrict__ att_d,
                                                        const float* __restrict__ bias,
                                                        float* __restrict__ out) {
    int v = blockIdx.x * 4 + (threadIdx.x >> 6);
    if (v >= NN) return;
    int lane = threadIdx.x & 63;
    int e0 = rs[v], e1 = rs[v + 1];
    int c0 = lane * 2;
    int h0 = lane >> 4;                    // head = c0/32
    float2 adv = att_d[v * 4 + h0];

    float ap0 = 0.f, ap1 = 0.f, ag0 = 0.f, ag1 = 0.f;
    float dp = 0.f, dg = 0.f;

    int j = e0;
    for (; j + 1 < e1; j += 2) {
        int s0 = csr[j], s1 = csr[j + 1];
        float2 as0 = att_s[s0 * 4 + h0];
        float2 as1 = att_s[s1 * 4 + h0];
        float2 xp0 = *(const float2*)(xpp + (long)s0 * 128 + c0);
        float2 xg0 = *(const float2*)(xpg + (long)s0 * 128 + c0);
        float2 xp1 = *(const float2*)(xpp + (long)s1 * 128 + c0);
        float2 xg1 = *(const float2*)(xpg + (long)s1 * 128 + c0);
        float ep0 = as0.x + adv.x; ep0 = (ep0 > 0.f) ? ep0 : NEG * ep0;
        float eg0 = as0.y + adv.y; eg0 = (eg0 > 0.f) ? eg0 : NEG * eg0;
        float ep1 = as1.x + adv.x; ep1 = (ep1 > 0.f) ? ep1 : NEG * ep1;
        float eg1 = as1.y + adv.y; eg1 = (eg1 > 0.f) ? eg1 : NEG * eg1;
        float wp0 = __expf(ep0), wg0 = __expf(eg0);
        float wp1 = __expf(ep1), wg1 = __expf(eg1);
        dp += wp0 + wp1;
        dg += wg0 + wg1;
        ap0 += wp0 * xp0.x + wp1 * xp1.x;
        ap1 += wp0 * xp0.y + wp1 * xp1.y;
        ag0 += wg0 * xg0.x + wg1 * xg1.x;
        ag1 += wg0 * xg0.y + wg1 * xg1.y;
    }
    if (j < e1) {
        int s0 = csr[j];
        float2 as0 = att_s[s0 * 4 + h0];
        float2 xp0 = *(const float2*)(xpp + (long)s0 * 128 + c0);
        float2 xg0 = *(const float2*)(xpg + (long)s0 * 128 + c0);
        float ep0 = as0.x + adv.x; ep0 = (ep0 > 0.f) ? ep0 : NEG * ep0;
        float eg0 = as0.y + adv.y; eg0 = (eg0 > 0.f) ? eg0 : NEG * eg0;
        float wp0 = __expf(ep0), wg0 = __expf(eg0);
        dp += wp0; dg += wg0;
        ap0 += wp0 * xp0.x; ap1 += wp0 * xp0.y;
        ag0 += wg0 * xg0.x; ag1 += wg0 * xg0.y;
    }

    float ivp = 1.0f / dp, ivg = 1.0f / dg;
    float b0 = bias[c0], b1v = bias[c0 + 1];
    float* o = out + (long)v * 256;
    o[c0]           = fmaxf(ap0 * ivp + b0, 0.f);
    o[c0 + 1]       = fmaxf(ap1 * ivp + b1v, 0.f);
    o[128 + c0]     = fmaxf(ag0 * ivg + b0, 0.f);
    o[128 + c0 + 1] = fmaxf(ag1 * ivg + b1v, 0.f);
}

// ---------------------------------------------------------------------------
// Single-pass conv2 edge kernel (H=1, C=64, no relu).
// ---------------------------------------------------------------------------
__global__ __launch_bounds__(256) void conv2_edge(const int* __restrict__ rs, const int* __restrict__ csr,
                                                  const float* __restrict__ xp,
                                                  const float* __restrict__ asrc, const float* __restrict__ adst,
                                                  const float* __restrict__ bias,
                                                  float* __restrict__ out) {
    int v = blockIdx.x * 4 + (threadIdx.x >> 6);
    if (v >= NN) return;
    int lane = threadIdx.x & 63;
    int e0 = rs[v], e1 = rs[v + 1];
    float adv = adst[v];

    float acc = 0.f, d = 0.f;
    int j = e0;
    for (; j + 1 < e1; j += 2) {
        int s0 = csr[j], s1 = csr[j + 1];
        float as0 = asrc[s0], as1 = asrc[s1];
        float x0 = xp[(long)s0 * 64 + lane];
        float x1 = xp[(long)s1 * 64 + lane];
        float e0v = as0 + adv; e0v = (e0v > 0.f) ? e0v : NEG * e0v;
        float e1v = as1 + adv; e1v = (e1v > 0.f) ? e1v : NEG * e1v;
        float w0 = __expf(e0v), w1 = __expf(e1v);
        d += w0 + w1;
        acc += w0 * x0 + w1 * x1;
    }
    if (j < e1) {
        int s0 = csr[j];
        float as0 = asrc[s0];
        float x0 = xp[(long)s0 * 64 + lane];
        float e0v = as0 + adv; e0v = (e0v > 0.f) ? e0v : NEG * e0v;
        float w0 = __expf(e0v);
        d += w0;
        acc += w0 * x0;
    }
    out[(long)v * 64 + lane] = acc / d + bias[lane];
}

// ---------------------------------------------------------------------------
// Launch
// ---------------------------------------------------------------------------
extern "C" void kernel_launch(void* const* d_in, const int* in_sizes, int n_in,
                              void* d_out, int out_size, void* d_ws, size_t ws_size,
                              hipStream_t stream) {
    const float* x_ppi = (const float*)d_in[0];
    const float* x_go  = (const float*)d_in[1];
    const int*   ei    = (const int*)d_in[2];
    const float* W1    = (const float*)d_in[3];
    const float* as1   = (const float*)d_in[4];
    const float* ad1   = (const float*)d_in[5];
    const float* b1    = (const float*)d_in[6];
    const float* W2    = (const float*)d_in[7];
    const float* as2   = (const float*)d_in[8];
    const float* ad2   = (const float*)d_in[9];
    const float* b2    = (const float*)d_in[10];
    float* out = (float*)d_out;

    char* ws = (char*)d_ws;
    size_t off = 0;
    auto alloc = [&](size_t bytes) -> void* {
        void* p = ws + off;
        off = (off + bytes + 255) & ~(size_t)255;
        return p;
    };
    int* deg     = (int*)alloc((size_t)NN * 4);
    int* rs      = (int*)alloc((size_t)(NN + 1) * 4);
    int* cur     = (int*)alloc((size_t)NN * 4);
    int* part    = (int*)alloc(512 * 4);
    int* csr     = (int*)alloc((size_t)ET * 4);
    float* xp_p  = (float*)alloc((size_t)NN * 128 * 4);  // ppi features; reused for conv2 xp
    float* xp_g  = (float*)alloc((size_t)NN * 128 * 4);
    float2* atts = (float2*)alloc((size_t)NN * 4 * 8);
    float2* attd = (float2*)alloc((size_t)NN * 4 * 8);
    float* asr2  = (float*)alloc((size_t)NN * 4);
    float* ads2  = (float*)alloc((size_t)NN * 4);
    float* hbuf  = (float*)alloc((size_t)NN * 256 * 4);
    (void)ws_size; (void)in_sizes; (void)n_in; (void)out_size;

    const int NB = (NN + 255) / 256;        // 391
    const int EB = (ET + 255) / 256;        // 6641

    // CSR build (shared by all three convs)
    hipMemsetAsync(deg, 0, (size_t)NN * 4, stream);
    k_count<<<EB, 256, 0, stream>>>(ei, deg);
    k_part<<<NB, 256, 0, stream>>>(deg, part);
    k_scanp<<<1, 512, 0, stream>>>(part, NB);
    k_scan<<<NB, 256, 0, stream>>>(deg, part, rs, cur);
    k_scatter<<<EB, 256, 0, stream>>>(ei, cur, csr);

    // layer 1: two GEMMs, fused attn, fused single-pass edge conv
    gemm_kernel<128, 128, 128><<<(NN + 127) / 128, 256, 0, stream>>>(x_ppi, W1, xp_p, NN);
    gemm_kernel<128, 128, 128><<<(NN + 127) / 128, 256, 0, stream>>>(x_go, W1, xp_g, NN);
    attn1_fused<<<(NN * 4 + 255) / 256, 256, 0, stream>>>(xp_p, xp_g, as1, ad1, atts, attd, NN);
    conv1_edge_fused<<<NN / 4, 256, 0, stream>>>(rs, csr, xp_p, xp_g, atts, attd, b1, hbuf);

    // layer 2
    gemm_kernel<256, 64, 256><<<(NN + 255) / 256, 256, 0, stream>>>(hbuf, W2, xp_p, NN);
    attn2_kernel<<<(NN + 255) / 256, 256, 0, stream>>>(xp_p, as2, ad2, asr2, ads2, NN);
    conv2_edge<<<NN / 4, 256, 0, stream>>>(rs, csr, xp_p, asr2, ads2, b2, out);
}

// Round 3
// 749.022 us; speedup vs baseline: 1.4580x; 1.1985x over previous
//
#include <hip/hip_runtime.h>
#include <hip/hip_fp16.h>

// Problem constants (fixed by the reference)
constexpr int NN = 100000;          // nodes
constexpr int EE = 1600000;         // edges (without self loops)
constexpr int ET = EE + NN;         // edges + self loops
constexpr float NEG = 0.2f;

// ---------------------------------------------------------------------------
// CSR build: histogram -> scan -> scatter
// ---------------------------------------------------------------------------
__global__ __launch_bounds__(256) void k_count(const int* __restrict__ ei, int* __restrict__ deg) {
    int i = blockIdx.x * 256 + threadIdx.x;
    if (i >= ET) return;
    int dst = (i < EE) ? ei[EE + i] : (i - EE);
    atomicAdd(&deg[dst], 1);
}

__global__ __launch_bounds__(256) void k_part(const int* __restrict__ deg, int* __restrict__ part) {
    __shared__ int sh[256];
    int i = blockIdx.x * 256 + threadIdx.x;
    sh[threadIdx.x] = (i < NN) ? deg[i] : 0;
    __syncthreads();
    for (int o = 128; o; o >>= 1) {
        if (threadIdx.x < o) sh[threadIdx.x] += sh[threadIdx.x + o];
        __syncthreads();
    }
    if (threadIdx.x == 0) part[blockIdx.x] = sh[0];
}

__global__ __launch_bounds__(512) void k_scanp(int* __restrict__ part, int nb) {
    __shared__ int sh[512];
    int t = threadIdx.x;
    int v = (t < nb) ? part[t] : 0;
    sh[t] = v;
    __syncthreads();
    for (int o = 1; o < 512; o <<= 1) {
        int u = (t >= o) ? sh[t - o] : 0;
        __syncthreads();
        sh[t] += u;
        __syncthreads();
    }
    if (t < nb) part[t] = sh[t] - v;   // exclusive
}

__global__ __launch_bounds__(256) void k_scan(const int* __restrict__ deg, const int* __restrict__ part,
                                              int* __restrict__ rs, int* __restrict__ cur) {
    __shared__ int sh[256];
    int t = threadIdx.x;
    int i = blockIdx.x * 256 + t;
    int v = (i < NN) ? deg[i] : 0;
    sh[t] = v;
    __syncthreads();
    for (int o = 1; o < 256; o <<= 1) {
        int u = (t >= o) ? sh[t - o] : 0;
        __syncthreads();
        sh[t] += u;
        __syncthreads();
    }
    int incl = sh[t];
    int base = part[blockIdx.x];
    if (i < NN) {
        rs[i]  = base + incl - v;
        cur[i] = base + incl - v;
        if (i == NN - 1) rs[NN] = base + incl;
    }
}

__global__ __launch_bounds__(256) void k_scatter(const int* __restrict__ ei, int* __restrict__ cur,
                                                 int* __restrict__ csr) {
    int i = blockIdx.x * 256 + threadIdx.x;
    if (i >= ET) return;
    int src, dst;
    if (i < EE) { src = ei[i]; dst = ei[EE + i]; }
    else        { src = i - EE; dst = i - EE; }
    int pos = atomicAdd(&cur[dst], 1);
    csr[pos] = src;
}

// ---------------------------------------------------------------------------
// fp32 GEMM: xp = x @ W, fp16 output. Block computes ROWS x C tile, thread 8x8.
// OUT_MODE 0: pair-interleaved packed layout {p0,p1,g0,g1} per chunk,
//             row stride 256 halves, set_off in {0,2}.
// OUT_MODE 1: plain fp16 row of C halves.
// ---------------------------------------------------------------------------
template <int K, int C, int ROWS, int OUT_MODE>
__global__ __launch_bounds__(256) void gemm_kernel(const float* __restrict__ x, const float* __restrict__ W,
                                                   __half* __restrict__ xp, int n, int set_off) {
    constexpr int KB  = 32;
    constexpr int TCG = C / 8;        // col groups of 8
    constexpr int TRG = 256 / TCG;    // row groups of 8
    static_assert(ROWS == TRG * 8, "tile mismatch");
    __shared__ __align__(16) float xs[KB * ROWS];   // [k][row]
    __shared__ __align__(16) float wsm[KB * C];     // [k][col]

    const int tid = threadIdx.x;
    const int tc  = tid % TCG;
    const int tr  = tid / TCG;
    const long g0 = (long)blockIdx.x * ROWS;

    float acc[8][8];
#pragma unroll
    for (int i = 0; i < 8; i++)
#pragma unroll
        for (int j = 0; j < 8; j++) acc[i][j] = 0.f;

    for (int kb = 0; kb < K; kb += KB) {
        for (int idx = tid; idx < ROWS * 8; idx += 256) {
            int r = idx & (ROWS - 1);
            int q = idx / ROWS;          // 0..7 -> k chunk of 4
            long row = g0 + r;
            float4 v = make_float4(0.f, 0.f, 0.f, 0.f);
            if (row < n) v = *(const float4*)(x + row * (long)K + kb + q * 4);
            xs[(q * 4 + 0) * ROWS + r] = v.x;
            xs[(q * 4 + 1) * ROWS + r] = v.y;
            xs[(q * 4 + 2) * ROWS + r] = v.z;
            xs[(q * 4 + 3) * ROWS + r] = v.w;
        }
        for (int idx = tid; idx < KB * C / 4; idx += 256)
            ((float4*)wsm)[idx] = ((const float4*)(W + (long)kb * C))[idx];
        __syncthreads();

#pragma unroll 4
        for (int k = 0; k < KB; k++) {
            float xr[8], wr[8];
            *(float4*)(xr)     = *(const float4*)(xs + k * ROWS + tr * 8);
            *(float4*)(xr + 4) = *(const float4*)(xs + k * ROWS + tr * 8 + 4);
            *(float4*)(wr)     = *(const float4*)(wsm + k * C + tc * 8);
            *(float4*)(wr + 4) = *(const float4*)(wsm + k * C + tc * 8 + 4);
#pragma unroll
            for (int i = 0; i < 8; i++)
#pragma unroll
                for (int j = 0; j < 8; j++) acc[i][j] += xr[i] * wr[j];
        }
        __syncthreads();
    }

#pragma unroll
    for (int i = 0; i < 8; i++) {
        long row = g0 + tr * 8 + i;
        if (row >= n) continue;
        if (OUT_MODE == 0) {
            // channels tc*8+2q, tc*8+2q+1 -> chunk (tc*4+q), halves [chunk*4+set_off ..]
            __half* o = xp + row * 256 + set_off;
#pragma unroll
            for (int q = 0; q < 4; q++) {
                __half2 hv = __floats2half2_rn(acc[i][2 * q], acc[i][2 * q + 1]);
                *(__half2*)(o + (tc * 4 + q) * 4) = hv;
            }
        } else {
            __half* o = xp + row * (long)C + tc * 8;
#pragma unroll
            for (int q = 0; q < 4; q++) {
                __half2 hv = __floats2half2_rn(acc[i][2 * q], acc[i][2 * q + 1]);
                *(__half2*)(o + 2 * q) = hv;
            }
        }
    }
}

// ---------------------------------------------------------------------------
// Fused attention coefficients for conv1 from packed fp16 xpc.
// att_s[v*4+h] = { <xp_ppi[v,h,:],as1[h,:]>, <xp_go[v,h,:],as1[h,:]> }
// ---------------------------------------------------------------------------
__global__ __launch_bounds__(256) void attn1_fused(const __half2* __restrict__ xpc,
                                                   const float* __restrict__ as_w, const float* __restrict__ ad_w,
                                                   float2* __restrict__ att_s, float2* __restrict__ att_d, int n) {
    int idx = blockIdx.x * 256 + threadIdx.x;
    if (idx >= n * 4) return;
    int v = idx >> 2, hh = idx & 3;
    const __half2* row = xpc + (long)v * 128 + hh * 32;   // 16 chunks x 2 half2
    const float* a1 = as_w + hh * 32;
    const float* a2 = ad_w + hh * 32;
    float sp1 = 0.f, sp2 = 0.f, sg1 = 0.f, sg2 = 0.f;
#pragma unroll
    for (int t = 0; t < 16; t++) {
        __half2 pp = row[2 * t];
        __half2 gg = row[2 * t + 1];
        float2 fp = __half22float2(pp);
        float2 fg = __half22float2(gg);
        float2 w1 = *(const float2*)(a1 + 2 * t);
        float2 w2 = *(const float2*)(a2 + 2 * t);
        sp1 += fp.x * w1.x + fp.y * w1.y;
        sp2 += fp.x * w2.x + fp.y * w2.y;
        sg1 += fg.x * w1.x + fg.y * w1.y;
        sg2 += fg.x * w2.x + fg.y * w2.y;
    }
    att_s[idx] = make_float2(sp1, sg1);
    att_d[idx] = make_float2(sp2, sg2);
}

// attention for conv2 (H=1, C=64), fp16 xp
__global__ __launch_bounds__(256) void attn2_kernel(const __half2* __restrict__ xp,
                                                    const float* __restrict__ as_w, const float* __restrict__ ad_w,
                                                    float* __restrict__ asrc, float* __restrict__ adst, int n) {
    int v = blockIdx.x * 256 + threadIdx.x;
    if (v >= n) return;
    const __half2* p = xp + (long)v * 32;
    float s1 = 0.f, s2 = 0.f;
#pragma unroll
    for (int c = 0; c < 32; c++) {
        float2 xv = __half22float2(p[c]);
        float2 w1 = *(const float2*)(as_w + 2 * c);
        float2 w2 = *(const float2*)(ad_w + 2 * c);
        s1 += xv.x * w1.x + xv.y * w1.y;
        s2 += xv.x * w2.x + xv.y * w2.y;
    }
    asrc[v] = s1;
    adst[v] = s2;
}

// ---------------------------------------------------------------------------
// Fused single-pass conv1 edge kernel. One wave per dst node; lane l carries
// channels {2l,2l+1} of both feature sets via ONE 8B gather from the packed
// fp16 layout. Unnormalized softmax accumulated inline, one divide at end.
// 4x unrolled: 4 row gathers + 4 attn gathers in flight.
// ---------------------------------------------------------------------------
__global__ __launch_bounds__(256) void conv1_edge_fused(const int* __restrict__ rs, const int* __restrict__ csr,
                                                        const uint2* __restrict__ xpc,
                                                        const float2* __restrict__ att_s, const float2* __restrict__ att_d,
                                                        const float* __restrict__ bias,
                                                        float* __restrict__ out) {
    int v = blockIdx.x * 4 + (threadIdx.x >> 6);
    if (v >= NN) return;
    int lane = threadIdx.x & 63;
    int e0 = rs[v], e1 = rs[v + 1];
    int c0 = lane * 2;
    int h0 = lane >> 4;                    // head = c0/32
    float2 adv = att_d[v * 4 + h0];

    float ap0 = 0.f, ap1 = 0.f, ag0 = 0.f, ag1 = 0.f;
    float dp = 0.f, dg = 0.f;

    auto process = [&](float2 a, uint2 r) {
        float ep = a.x + adv.x; ep = (ep > 0.f) ? ep : NEG * ep;
        float eg = a.y + adv.y; eg = (eg > 0.f) ? eg : NEG * eg;
        float wp = __expf(ep), wg = __expf(eg);
        dp += wp; dg += wg;
        float2 fp = __half22float2(*(__half2*)&r.x);
        float2 fg = __half22float2(*(__half2*)&r.y);
        ap0 += wp * fp.x; ap1 += wp * fp.y;
        ag0 += wg * fg.x; ag1 += wg * fg.y;
    };

    int j = e0;
    for (; j + 3 < e1; j += 4) {
        int s0 = csr[j], s1 = csr[j + 1], s2 = csr[j + 2], s3 = csr[j + 3];
        float2 a0 = att_s[s0 * 4 + h0];
        float2 a1 = att_s[s1 * 4 + h0];
        float2 a2 = att_s[s2 * 4 + h0];
        float2 a3 = att_s[s3 * 4 + h0];
        uint2 r0 = xpc[(long)s0 * 64 + lane];
        uint2 r1 = xpc[(long)s1 * 64 + lane];
        uint2 r2 = xpc[(long)s2 * 64 + lane];
        uint2 r3 = xpc[(long)s3 * 64 + lane];
        process(a0, r0); process(a1, r1); process(a2, r2); process(a3, r3);
    }
    for (; j < e1; ++j) {
        int s0 = csr[j];
        float2 a0 = att_s[s0 * 4 + h0];
        uint2 r0 = xpc[(long)s0 * 64 + lane];
        process(a0, r0);
    }

    float ivp = 1.0f / dp, ivg = 1.0f / dg;
    float b0 = bias[c0], b1v = bias[c0 + 1];
    float* o = out + (long)v * 256;
    o[c0]           = fmaxf(ap0 * ivp + b0, 0.f);
    o[c0 + 1]       = fmaxf(ap1 * ivp + b1v, 0.f);
    o[128 + c0]     = fmaxf(ag0 * ivg + b0, 0.f);
    o[128 + c0 + 1] = fmaxf(ag1 * ivg + b1v, 0.f);
}

// ---------------------------------------------------------------------------
// Single-pass conv2 edge kernel (H=1, C=64, fp16 xp, no relu), 4x unrolled.
// ---------------------------------------------------------------------------
__global__ __launch_bounds__(256) void conv2_edge(const int* __restrict__ rs, const int* __restrict__ csr,
                                                  const __half* __restrict__ xp,
                                                  const float* __restrict__ asrc, const float* __restrict__ adst,
                                                  const float* __restrict__ bias,
                                                  float* __restrict__ out) {
    int v = blockIdx.x * 4 + (threadIdx.x >> 6);
    if (v >= NN) return;
    int lane = threadIdx.x & 63;
    int e0 = rs[v], e1 = rs[v + 1];
    float adv = adst[v];

    float acc = 0.f, d = 0.f;
    auto process = [&](float as, float xv) {
        float e = as + adv; e = (e > 0.f) ? e : NEG * e;
        float w = __expf(e);
        d += w;
        acc += w * xv;
    };

    int j = e0;
    for (; j + 3 < e1; j += 4) {
        int s0 = csr[j], s1 = csr[j + 1], s2 = csr[j + 2], s3 = csr[j + 3];
        float a0 = asrc[s0], a1 = asrc[s1], a2 = asrc[s2], a3 = asrc[s3];
        float x0 = __half2float(xp[(long)s0 * 64 + lane]);
        float x1 = __half2float(xp[(long)s1 * 64 + lane]);
        float x2 = __half2float(xp[(long)s2 * 64 + lane]);
        float x3 = __half2float(xp[(long)s3 * 64 + lane]);
        process(a0, x0); process(a1, x1); process(a2, x2); process(a3, x3);
    }
    for (; j < e1; ++j) {
        int s0 = csr[j];
        process(asrc[s0], __half2float(xp[(long)s0 * 64 + lane]));
    }
    out[(long)v * 64 + lane] = acc / d + bias[lane];
}

// ---------------------------------------------------------------------------
// Launch
// ---------------------------------------------------------------------------
extern "C" void kernel_launch(void* const* d_in, const int* in_sizes, int n_in,
                              void* d_out, int out_size, void* d_ws, size_t ws_size,
                              hipStream_t stream) {
    const float* x_ppi = (const float*)d_in[0];
    const float* x_go  = (const float*)d_in[1];
    const int*   ei    = (const int*)d_in[2];
    const float* W1    = (const float*)d_in[3];
    const float* as1   = (const float*)d_in[4];
    const float* ad1   = (const float*)d_in[5];
    const float* b1    = (const float*)d_in[6];
    const float* W2    = (const float*)d_in[7];
    const float* as2   = (const float*)d_in[8];
    const float* ad2   = (const float*)d_in[9];
    const float* b2    = (const float*)d_in[10];
    float* out = (float*)d_out;

    char* ws = (char*)d_ws;
    size_t off = 0;
    auto alloc = [&](size_t bytes) -> void* {
        void* p = ws + off;
        off = (off + bytes + 255) & ~(size_t)255;
        return p;
    };
    int* deg     = (int*)alloc((size_t)NN * 4);
    int* rs      = (int*)alloc((size_t)(NN + 1) * 4);
    int* cur     = (int*)alloc((size_t)NN * 4);
    int* part    = (int*)alloc(512 * 4);
    int* csr     = (int*)alloc((size_t)ET * 4);
    __half* xpc  = (__half*)alloc((size_t)NN * 256 * 2);   // packed {p0,p1,g0,g1} fp16
    __half* xp2  = (__half*)alloc((size_t)NN * 64 * 2);    // conv2 features fp16
    float2* atts = (float2*)alloc((size_t)NN * 4 * 8);
    float2* attd = (float2*)alloc((size_t)NN * 4 * 8);
    float* asr2  = (float*)alloc((size_t)NN * 4);
    float* ads2  = (float*)alloc((size_t)NN * 4);
    float* hbuf  = (float*)alloc((size_t)NN * 256 * 4);
    (void)ws_size; (void)in_sizes; (void)n_in; (void)out_size;

    const int NB = (NN + 255) / 256;        // 391
    const int EB = (ET + 255) / 256;        // 6641

    // CSR build (shared by all three convs)
    hipMemsetAsync(deg, 0, (size_t)NN * 4, stream);
    k_count<<<EB, 256, 0, stream>>>(ei, deg);
    k_part<<<NB, 256, 0, stream>>>(deg, part);
    k_scanp<<<1, 512, 0, stream>>>(part, NB);
    k_scan<<<NB, 256, 0, stream>>>(deg, part, rs, cur);
    k_scatter<<<EB, 256, 0, stream>>>(ei, cur, csr);

    // layer 1: two GEMMs into packed fp16, fused attn, fused edge conv
    gemm_kernel<128, 128, 128, 0><<<(NN + 127) / 128, 256, 0, stream>>>(x_ppi, W1, xpc, NN, 0);
    gemm_kernel<128, 128, 128, 0><<<(NN + 127) / 128, 256, 0, stream>>>(x_go, W1, xpc, NN, 2);
    attn1_fused<<<(NN * 4 + 255) / 256, 256, 0, stream>>>((const __half2*)xpc, as1, ad1, atts, attd, NN);
    conv1_edge_fused<<<NN / 4, 256, 0, stream>>>(rs, csr, (const uint2*)xpc, atts, attd, b1, hbuf);

    // layer 2
    gemm_kernel<256, 64, 256, 1><<<(NN + 255) / 256, 256, 0, stream>>>(hbuf, W2, xp2, NN, 0);
    attn2_kernel<<<(NN + 255) / 256, 256, 0, stream>>>((const __half2*)xp2, as2, ad2, asr2, ads2, NN);
    conv2_edge<<<NN / 4, 256, 0, stream>>>(rs, csr, xp2, asr2, ads2, b2, out);
}

// Round 4
// 739.823 us; speedup vs baseline: 1.4762x; 1.0124x over previous
//
#include <hip/hip_runtime.h>
#include <hip/hip_fp16.h>

// Problem constants (fixed by the reference)
constexpr int NN = 100000;          // nodes
constexpr int EE = 1600000;         // edges (without self loops)
constexpr int ET = EE + NN;         // edges + self loops
constexpr float NEG = 0.2f;

// ---------------------------------------------------------------------------
// CSR build: histogram -> scan -> scatter (scatter also records dst per slot)
// ---------------------------------------------------------------------------
__global__ __launch_bounds__(256) void k_count(const int* __restrict__ ei, int* __restrict__ deg) {
    int i = blockIdx.x * 256 + threadIdx.x;
    if (i >= ET) return;
    int dst = (i < EE) ? ei[EE + i] : (i - EE);
    atomicAdd(&deg[dst], 1);
}

__global__ __launch_bounds__(256) void k_part(const int* __restrict__ deg, int* __restrict__ part) {
    __shared__ int sh[256];
    int i = blockIdx.x * 256 + threadIdx.x;
    sh[threadIdx.x] = (i < NN) ? deg[i] : 0;
    __syncthreads();
    for (int o = 128; o; o >>= 1) {
        if (threadIdx.x < o) sh[threadIdx.x] += sh[threadIdx.x + o];
        __syncthreads();
    }
    if (threadIdx.x == 0) part[blockIdx.x] = sh[0];
}

__global__ __launch_bounds__(512) void k_scanp(int* __restrict__ part, int nb) {
    __shared__ int sh[512];
    int t = threadIdx.x;
    int v = (t < nb) ? part[t] : 0;
    sh[t] = v;
    __syncthreads();
    for (int o = 1; o < 512; o <<= 1) {
        int u = (t >= o) ? sh[t - o] : 0;
        __syncthreads();
        sh[t] += u;
        __syncthreads();
    }
    if (t < nb) part[t] = sh[t] - v;   // exclusive
}

__global__ __launch_bounds__(256) void k_scan(const int* __restrict__ deg, const int* __restrict__ part,
                                              int* __restrict__ rs, int* __restrict__ cur) {
    __shared__ int sh[256];
    int t = threadIdx.x;
    int i = blockIdx.x * 256 + t;
    int v = (i < NN) ? deg[i] : 0;
    sh[t] = v;
    __syncthreads();
    for (int o = 1; o < 256; o <<= 1) {
        int u = (t >= o) ? sh[t - o] : 0;
        __syncthreads();
        sh[t] += u;
        __syncthreads();
    }
    int incl = sh[t];
    int base = part[blockIdx.x];
    if (i < NN) {
        rs[i]  = base + incl - v;
        cur[i] = base + incl - v;
        if (i == NN - 1) rs[NN] = base + incl;
    }
}

__global__ __launch_bounds__(256) void k_scatter(const int* __restrict__ ei, int* __restrict__ cur,
                                                 int* __restrict__ csr, int* __restrict__ dstv) {
    int i = blockIdx.x * 256 + threadIdx.x;
    if (i >= ET) return;
    int src, dst;
    if (i < EE) { src = ei[i]; dst = ei[EE + i]; }
    else        { src = i - EE; dst = i - EE; }
    int pos = atomicAdd(&cur[dst], 1);
    csr[pos]  = src;
    dstv[pos] = dst;
}

// ---------------------------------------------------------------------------
// fp32 GEMM: xp = x @ W, fp16 output. Block computes ROWS x C tile, thread 8x8.
// OUT_MODE 0: pair-interleaved packed layout {p0,p1,g0,g1} per chunk,
//             row stride 256 halves, set_off in {0,2}.
// OUT_MODE 1: plain fp16 row of C halves.
// ---------------------------------------------------------------------------
template <int K, int C, int ROWS, int OUT_MODE>
__global__ __launch_bounds__(256) void gemm_kernel(const float* __restrict__ x, const float* __restrict__ W,
                                                   __half* __restrict__ xp, int n, int set_off) {
    constexpr int KB  = 32;
    constexpr int TCG = C / 8;        // col groups of 8
    constexpr int TRG = 256 / TCG;    // row groups of 8
    static_assert(ROWS == TRG * 8, "tile mismatch");
    __shared__ __align__(16) float xs[KB * ROWS];   // [k][row]
    __shared__ __align__(16) float wsm[KB * C];     // [k][col]

    const int tid = threadIdx.x;
    const int tc  = tid % TCG;
    const int tr  = tid / TCG;
    const long g0 = (long)blockIdx.x * ROWS;

    float acc[8][8];
#pragma unroll
    for (int i = 0; i < 8; i++)
#pragma unroll
        for (int j = 0; j < 8; j++) acc[i][j] = 0.f;

    for (int kb = 0; kb < K; kb += KB) {
        for (int idx = tid; idx < ROWS * 8; idx += 256) {
            int r = idx & (ROWS - 1);
            int q = idx / ROWS;          // 0..7 -> k chunk of 4
            long row = g0 + r;
            float4 v = make_float4(0.f, 0.f, 0.f, 0.f);
            if (row < n) v = *(const float4*)(x + row * (long)K + kb + q * 4);
            xs[(q * 4 + 0) * ROWS + r] = v.x;
            xs[(q * 4 + 1) * ROWS + r] = v.y;
            xs[(q * 4 + 2) * ROWS + r] = v.z;
            xs[(q * 4 + 3) * ROWS + r] = v.w;
        }
        for (int idx = tid; idx < KB * C / 4; idx += 256)
            ((float4*)wsm)[idx] = ((const float4*)(W + (long)kb * C))[idx];
        __syncthreads();

#pragma unroll 4
        for (int k = 0; k < KB; k++) {
            float xr[8], wr[8];
            *(float4*)(xr)     = *(const float4*)(xs + k * ROWS + tr * 8);
            *(float4*)(xr + 4) = *(const float4*)(xs + k * ROWS + tr * 8 + 4);
            *(float4*)(wr)     = *(const float4*)(wsm + k * C + tc * 8);
            *(float4*)(wr + 4) = *(const float4*)(wsm + k * C + tc * 8 + 4);
#pragma unroll
            for (int i = 0; i < 8; i++)
#pragma unroll
                for (int j = 0; j < 8; j++) acc[i][j] += xr[i] * wr[j];
        }
        __syncthreads();
    }

#pragma unroll
    for (int i = 0; i < 8; i++) {
        long row = g0 + tr * 8 + i;
        if (row >= n) continue;
        if (OUT_MODE == 0) {
            __half* o = xp + row * 256 + set_off;
#pragma unroll
            for (int q = 0; q < 4; q++) {
                __half2 hv = __floats2half2_rn(acc[i][2 * q], acc[i][2 * q + 1]);
                *(__half2*)(o + (tc * 4 + q) * 4) = hv;
            }
        } else {
            __half* o = xp + row * (long)C + tc * 8;
#pragma unroll
            for (int q = 0; q < 4; q++) {
                __half2 hv = __floats2half2_rn(acc[i][2 * q], acc[i][2 * q + 1]);
                *(__half2*)(o + 2 * q) = hv;
            }
        }
    }
}

// ---------------------------------------------------------------------------
// Fused attention coefficients for conv1 from packed fp16 xpc.
// att_s[v*4+h] = { <xp_ppi[v,h,:],as1[h,:]>, <xp_go[v,h,:],as1[h,:]> }
// ---------------------------------------------------------------------------
__global__ __launch_bounds__(256) void attn1_fused(const __half2* __restrict__ xpc,
                                                   const float* __restrict__ as_w, const float* __restrict__ ad_w,
                                                   float2* __restrict__ att_s, float2* __restrict__ att_d, int n) {
    int idx = blockIdx.x * 256 + threadIdx.x;
    if (idx >= n * 4) return;
    int v = idx >> 2, hh = idx & 3;
    const __half2* row = xpc + (long)v * 128 + hh * 32;   // 16 chunks x 2 half2
    const float* a1 = as_w + hh * 32;
    const float* a2 = ad_w + hh * 32;
    float sp1 = 0.f, sp2 = 0.f, sg1 = 0.f, sg2 = 0.f;
#pragma unroll
    for (int t = 0; t < 16; t++) {
        __half2 pp = row[2 * t];
        __half2 gg = row[2 * t + 1];
        float2 fp = __half22float2(pp);
        float2 fg = __half22float2(gg);
        float2 w1 = *(const float2*)(a1 + 2 * t);
        float2 w2 = *(const float2*)(a2 + 2 * t);
        sp1 += fp.x * w1.x + fp.y * w1.y;
        sp2 += fp.x * w2.x + fp.y * w2.y;
        sg1 += fg.x * w1.x + fg.y * w1.y;
        sg2 += fg.x * w2.x + fg.y * w2.y;
    }
    att_s[idx] = make_float2(sp1, sg1);
    att_d[idx] = make_float2(sp2, sg2);
}

// attention for conv2 (H=1, C=64), fp16 xp
__global__ __launch_bounds__(256) void attn2_kernel(const __half2* __restrict__ xp,
                                                    const float* __restrict__ as_w, const float* __restrict__ ad_w,
                                                    float* __restrict__ asrc, float* __restrict__ adst, int n) {
    int v = blockIdx.x * 256 + threadIdx.x;
    if (v >= n) return;
    const __half2* p = xp + (long)v * 32;
    float s1 = 0.f, s2 = 0.f;
#pragma unroll
    for (int c = 0; c < 32; c++) {
        float2 xv = __half22float2(p[c]);
        float2 w1 = *(const float2*)(as_w + 2 * c);
        float2 w2 = *(const float2*)(ad_w + 2 * c);
        s1 += xv.x * w1.x + xv.y * w1.y;
        s2 += xv.x * w2.x + xv.y * w2.y;
    }
    asrc[v] = s1;
    adst[v] = s2;
}

// ---------------------------------------------------------------------------
// Per-edge exp-weight precompute for conv1: one thread per CSR slot computes
// the 8 softmax numerator weights (4 heads x {ppi,go}) ONCE (vs 16x redundant
// in the edge loop) and stores them sequentially (32 B/edge).
// dstv is sorted (CSR order) so att_d reads are broadcast/sequential.
// ---------------------------------------------------------------------------
__global__ __launch_bounds__(256) void w1prep(const int* __restrict__ csr, const int* __restrict__ dstv,
                                              const float4* __restrict__ att_s4, const float4* __restrict__ att_d4,
                                              float4* __restrict__ wb4) {
    int j = blockIdx.x * 256 + threadIdx.x;
    if (j >= ET) return;
    int s = csr[j], v = dstv[j];
    float4 s0 = att_s4[s * 2], s1 = att_s4[s * 2 + 1];
    float4 d0 = att_d4[v * 2], d1 = att_d4[v * 2 + 1];
    auto w = [](float e) { e = (e > 0.f) ? e : NEG * e; return __expf(e); };
    float4 w0, w1;
    w0.x = w(s0.x + d0.x); w0.y = w(s0.y + d0.y);
    w0.z = w(s0.z + d0.z); w0.w = w(s0.w + d0.w);
    w1.x = w(s1.x + d1.x); w1.y = w(s1.y + d1.y);
    w1.z = w(s1.z + d1.z); w1.w = w(s1.w + d1.w);
    wb4[j * 2]     = w0;
    wb4[j * 2 + 1] = w1;
}

// Per-edge exp-weight for conv2 (H=1): 4 B/edge.
__global__ __launch_bounds__(256) void w2prep(const int* __restrict__ csr, const int* __restrict__ dstv,
                                              const float* __restrict__ asrc, const float* __restrict__ adst,
                                              float* __restrict__ w2b) {
    int j = blockIdx.x * 256 + threadIdx.x;
    if (j >= ET) return;
    float e = asrc[csr[j]] + adst[dstv[j]];
    e = (e > 0.f) ? e : NEG * e;
    w2b[j] = __expf(e);
}

// ---------------------------------------------------------------------------
// Fused single-pass conv1 edge kernel. One wave per dst node; lane l carries
// channels {2l,2l+1} of both feature sets via ONE 8B gather from the packed
// fp16 layout; weights come precomputed (sequential 8 B load per lane).
// 8x unrolled: 8 row gathers in flight.
// ---------------------------------------------------------------------------
__global__ __launch_bounds__(256) void conv1_edge_fused(const int* __restrict__ rs, const int* __restrict__ csr,
                                                        const uint2* __restrict__ xpc,
                                                        const float2* __restrict__ wb,
                                                        const float* __restrict__ bias,
                                                        float* __restrict__ out) {
    int v = blockIdx.x * 4 + (threadIdx.x >> 6);
    if (v >= NN) return;
    int lane = threadIdx.x & 63;
    int e0 = rs[v], e1 = rs[v + 1];
    int c0 = lane * 2;
    int h0 = lane >> 4;                    // head = c0/32

    float ap0 = 0.f, ap1 = 0.f, ag0 = 0.f, ag1 = 0.f;
    float dp = 0.f, dg = 0.f;

    auto process = [&](float2 wv, uint2 r) {
        dp += wv.x; dg += wv.y;
        float2 fp = __half22float2(*(__half2*)&r.x);
        float2 fg = __half22float2(*(__half2*)&r.y);
        ap0 += wv.x * fp.x; ap1 += wv.x * fp.y;
        ag0 += wv.y * fg.x; ag1 += wv.y * fg.y;
    };

    int j = e0;
    for (; j + 7 < e1; j += 8) {
        int s[8];
#pragma unroll
        for (int q = 0; q < 8; q++) s[q] = csr[j + q];
        float2 wv[8];
        uint2 r[8];
#pragma unroll
        for (int q = 0; q < 8; q++) wv[q] = wb[(j + q) * 4 + h0];
#pragma unroll
        for (int q = 0; q < 8; q++) r[q] = xpc[(long)s[q] * 64 + lane];
#pragma unroll
        for (int q = 0; q < 8; q++) process(wv[q], r[q]);
    }
    for (; j < e1; ++j) {
        float2 wv = wb[j * 4 + h0];
        uint2 r = xpc[(long)csr[j] * 64 + lane];
        process(wv, r);
    }

    float ivp = 1.0f / dp, ivg = 1.0f / dg;
    float b0 = bias[c0], b1v = bias[c0 + 1];
    float* o = out + (long)v * 256;
    o[c0]           = fmaxf(ap0 * ivp + b0, 0.f);
    o[c0 + 1]       = fmaxf(ap1 * ivp + b1v, 0.f);
    o[128 + c0]     = fmaxf(ag0 * ivg + b0, 0.f);
    o[128 + c0 + 1] = fmaxf(ag1 * ivg + b1v, 0.f);
}

// ---------------------------------------------------------------------------
// Single-pass conv2 edge kernel (H=1, C=64, fp16 xp), precomputed weights
// (wave-uniform scalar load), 8x unrolled.
// ---------------------------------------------------------------------------
__global__ __launch_bounds__(256) void conv2_edge(const int* __restrict__ rs, const int* __restrict__ csr,
                                                  const __half* __restrict__ xp,
                                                  const float* __restrict__ w2b,
                                                  const float* __restrict__ bias,
                                                  float* __restrict__ out) {
    int v = blockIdx.x * 4 + (threadIdx.x >> 6);
    if (v >= NN) return;
    int lane = threadIdx.x & 63;
    int e0 = rs[v], e1 = rs[v + 1];

    float acc = 0.f, d = 0.f;
    int j = e0;
    for (; j + 7 < e1; j += 8) {
        int s[8];
#pragma unroll
        for (int q = 0; q < 8; q++) s[q] = csr[j + q];
        float w[8];
#pragma unroll
        for (int q = 0; q < 8; q++) w[q] = w2b[j + q];
        float x[8];
#pragma unroll
        for (int q = 0; q < 8; q++) x[q] = __half2float(xp[(long)s[q] * 64 + lane]);
#pragma unroll
        for (int q = 0; q < 8; q++) { d += w[q]; acc += w[q] * x[q]; }
    }
    for (; j < e1; ++j) {
        float w = w2b[j];
        float x = __half2float(xp[(long)csr[j] * 64 + lane]);
        d += w; acc += w * x;
    }
    out[(long)v * 64 + lane] = acc / d + bias[lane];
}

// ---------------------------------------------------------------------------
// Launch
// ---------------------------------------------------------------------------
extern "C" void kernel_launch(void* const* d_in, const int* in_sizes, int n_in,
                              void* d_out, int out_size, void* d_ws, size_t ws_size,
                              hipStream_t stream) {
    const float* x_ppi = (const float*)d_in[0];
    const float* x_go  = (const float*)d_in[1];
    const int*   ei    = (const int*)d_in[2];
    const float* W1    = (const float*)d_in[3];
    const float* as1   = (const float*)d_in[4];
    const float* ad1   = (const float*)d_in[5];
    const float* b1    = (const float*)d_in[6];
    const float* W2    = (const float*)d_in[7];
    const float* as2   = (const float*)d_in[8];
    const float* ad2   = (const float*)d_in[9];
    const float* b2    = (const float*)d_in[10];
    float* out = (float*)d_out;

    char* ws = (char*)d_ws;
    size_t off = 0;
    auto alloc = [&](size_t bytes) -> void* {
        void* p = ws + off;
        off = (off + bytes + 255) & ~(size_t)255;
        return p;
    };
    int* deg     = (int*)alloc((size_t)NN * 4);
    int* rs      = (int*)alloc((size_t)(NN + 1) * 4);
    int* cur     = (int*)alloc((size_t)NN * 4);
    int* part    = (int*)alloc(512 * 4);
    int* csr     = (int*)alloc((size_t)ET * 4);
    int* dstv    = (int*)alloc((size_t)ET * 4);
    __half* xpc  = (__half*)alloc((size_t)NN * 256 * 2);   // packed {p0,p1,g0,g1} fp16
    __half* xp2  = (__half*)alloc((size_t)NN * 64 * 2);    // conv2 features fp16
    float2* atts = (float2*)alloc((size_t)NN * 4 * 8);
    float2* attd = (float2*)alloc((size_t)NN * 4 * 8);
    float* asr2  = (float*)alloc((size_t)NN * 4);
    float* ads2  = (float*)alloc((size_t)NN * 4);
    float* wb1   = (float*)alloc((size_t)ET * 32);         // 8 fp32 weights / edge
    float* w2b   = (float*)alloc((size_t)ET * 4);
    float* hbuf  = (float*)alloc((size_t)NN * 256 * 4);
    (void)ws_size; (void)in_sizes; (void)n_in; (void)out_size;

    const int NB = (NN + 255) / 256;        // 391
    const int EB = (ET + 255) / 256;        // 6641

    // CSR build (shared by all three convs)
    hipMemsetAsync(deg, 0, (size_t)NN * 4, stream);
    k_count<<<EB, 256, 0, stream>>>(ei, deg);
    k_part<<<NB, 256, 0, stream>>>(deg, part);
    k_scanp<<<1, 512, 0, stream>>>(part, NB);
    k_scan<<<NB, 256, 0, stream>>>(deg, part, rs, cur);
    k_scatter<<<EB, 256, 0, stream>>>(ei, cur, csr, dstv);

    // layer 1: two GEMMs into packed fp16, fused attn, weight prep, edge conv
    gemm_kernel<128, 128, 128, 0><<<(NN + 127) / 128, 256, 0, stream>>>(x_ppi, W1, xpc, NN, 0);
    gemm_kernel<128, 128, 128, 0><<<(NN + 127) / 128, 256, 0, stream>>>(x_go, W1, xpc, NN, 2);
    attn1_fused<<<(NN * 4 + 255) / 256, 256, 0, stream>>>((const __half2*)xpc, as1, ad1, atts, attd, NN);
    w1prep<<<EB, 256, 0, stream>>>(csr, dstv, (const float4*)atts, (const float4*)attd, (float4*)wb1);
    conv1_edge_fused<<<NN / 4, 256, 0, stream>>>(rs, csr, (const uint2*)xpc, (const float2*)wb1, b1, hbuf);

    // layer 2
    gemm_kernel<256, 64, 256, 1><<<(NN + 255) / 256, 256, 0, stream>>>(hbuf, W2, xp2, NN, 0);
    attn2_kernel<<<(NN + 255) / 256, 256, 0, stream>>>((const __half2*)xp2, as2, ad2, asr2, ads2, NN);
    w2prep<<<EB, 256, 0, stream>>>(csr, dstv, asr2, ads2, w2b);
    conv2_edge<<<NN / 4, 256, 0, stream>>>(rs, csr, xp2, w2b, b2, out);
}

// Round 5
// 714.444 us; speedup vs baseline: 1.5286x; 1.0355x over previous
//
#include <hip/hip_runtime.h>
#include <hip/hip_fp16.h>

// Problem constants (fixed by the reference)
constexpr int NN = 100000;          // nodes
constexpr int EE = 1600000;         // edges (without self loops)
constexpr int ET = EE + NN;         // edges + self loops
constexpr float NEG = 0.2f;

typedef _Float16 f16x8 __attribute__((ext_vector_type(8)));
typedef _Float16 f16x4 __attribute__((ext_vector_type(4)));
typedef float    f32x4 __attribute__((ext_vector_type(4)));

// ---------------------------------------------------------------------------
// CSR build: histogram -> scan -> scatter (scatter also records dst per slot)
// ---------------------------------------------------------------------------
__global__ __launch_bounds__(256) void k_count(const int* __restrict__ ei, int* __restrict__ deg) {
    int i = blockIdx.x * 256 + threadIdx.x;
    if (i >= ET) return;
    int dst = (i < EE) ? ei[EE + i] : (i - EE);
    atomicAdd(&deg[dst], 1);
}

__global__ __launch_bounds__(256) void k_part(const int* __restrict__ deg, int* __restrict__ part) {
    __shared__ int sh[256];
    int i = blockIdx.x * 256 + threadIdx.x;
    sh[threadIdx.x] = (i < NN) ? deg[i] : 0;
    __syncthreads();
    for (int o = 128; o; o >>= 1) {
        if (threadIdx.x < o) sh[threadIdx.x] += sh[threadIdx.x + o];
        __syncthreads();
    }
    if (threadIdx.x == 0) part[blockIdx.x] = sh[0];
}

__global__ __launch_bounds__(512) void k_scanp(int* __restrict__ part, int nb) {
    __shared__ int sh[512];
    int t = threadIdx.x;
    int v = (t < nb) ? part[t] : 0;
    sh[t] = v;
    __syncthreads();
    for (int o = 1; o < 512; o <<= 1) {
        int u = (t >= o) ? sh[t - o] : 0;
        __syncthreads();
        sh[t] += u;
        __syncthreads();
    }
    if (t < nb) part[t] = sh[t] - v;   // exclusive
}

__global__ __launch_bounds__(256) void k_scan(const int* __restrict__ deg, const int* __restrict__ part,
                                              int* __restrict__ rs, int* __restrict__ cur) {
    __shared__ int sh[256];
    int t = threadIdx.x;
    int i = blockIdx.x * 256 + t;
    int v = (i < NN) ? deg[i] : 0;
    sh[t] = v;
    __syncthreads();
    for (int o = 1; o < 256; o <<= 1) {
        int u = (t >= o) ? sh[t - o] : 0;
        __syncthreads();
        sh[t] += u;
        __syncthreads();
    }
    int incl = sh[t];
    int base = part[blockIdx.x];
    if (i < NN) {
        rs[i]  = base + incl - v;
        cur[i] = base + incl - v;
        if (i == NN - 1) rs[NN] = base + incl;
    }
}

__global__ __launch_bounds__(256) void k_scatter(const int* __restrict__ ei, int* __restrict__ cur,
                                                 int* __restrict__ csr, int* __restrict__ dstv) {
    int i = blockIdx.x * 256 + threadIdx.x;
    if (i >= ET) return;
    int src, dst;
    if (i < EE) { src = ei[i]; dst = ei[EE + i]; }
    else        { src = i - EE; dst = i - EE; }
    int pos = atomicAdd(&cur[dst], 1);
    csr[pos]  = src;
    dstv[pos] = dst;
}

// ---------------------------------------------------------------------------
// MFMA GEMM: xp = x @ W (fp16 inputs to matrix core, fp32 accumulate).
// Block: 256 thr = 4 waves; 128 rows/block (wave w: rows w*32..w*32+32 as two
// 16-row MFMA tiles). K staged in 64-chunks; LDS padded +8 halves (2-way bank
// aliasing = free). A-operand: [m=lane&15][k=quad*8+j]; B from W^T with the
// same pattern; C/D: col=lane&15, row=quad*4+reg (verified layouts).
// OUT_MODE 0: packed {p0,p1,g0,g1} per channel pair, row stride 256 halves.
// OUT_MODE 1: plain fp16 row of C halves.
// SRCF32: x is fp32 (else fp16).
// ---------------------------------------------------------------------------
template <int K, int C, int OUT_MODE, bool SRCF32>
__global__ __launch_bounds__(256) void gemm_mfma(const void* __restrict__ xv, const float* __restrict__ W,
                                                 __half* __restrict__ xp, int n, int set_off) {
    constexpr int KC  = 64;          // K-chunk per stage
    constexpr int AST = KC + 8;      // padded LDS stride (halves)
    constexpr int NT  = C / 16;      // 16-col tiles
    constexpr int NST = K / KC;      // stages
    __shared__ _Float16 a_lds[128 * AST];
    __shared__ _Float16 w_lds[C * AST];

    const int tid  = threadIdx.x;
    const int w    = tid >> 6;
    const int lane = tid & 63;
    const int quad = lane >> 4;
    const int l16  = lane & 15;
    const long r0  = (long)blockIdx.x * 128;

    f32x4 acc[2][NT];
#pragma unroll
    for (int s = 0; s < 2; s++)
#pragma unroll
        for (int t = 0; t < NT; t++) acc[s][t] = (f32x4){0.f, 0.f, 0.f, 0.f};

    for (int st = 0; st < NST; ++st) {
        const int k0 = st * KC;
        // stage A: 128 rows x KC halves (convert fp32->fp16 if needed)
        for (int i = tid; i < 128 * (KC / 4); i += 256) {
            int r = i / (KC / 4);
            int q = i % (KC / 4);
            long row = r0 + r;
            f16x4 hv = (f16x4){0, 0, 0, 0};
            if (row < n) {
                if (SRCF32) {
                    float4 v = ((const float4*)xv)[row * (K / 4) + (k0 / 4) + q];
                    hv = (f16x4){(_Float16)v.x, (_Float16)v.y, (_Float16)v.z, (_Float16)v.w};
                } else {
                    hv = ((const f16x4*)xv)[row * (K / 4) + (k0 / 4) + q];
                }
            }
            *(f16x4*)&a_lds[r * AST + q * 4] = hv;
        }
        // stage W^T: w_lds[n][k] from W[k][n] (coalesced global reads over n)
        for (int i = tid; i < C * (KC / 4); i += 256) {
            int nn = i / (KC / 4);
            int kq = i % (KC / 4);
            f16x4 hv;
            hv.x = (_Float16)W[(long)(k0 + kq * 4 + 0) * C + nn];
            hv.y = (_Float16)W[(long)(k0 + kq * 4 + 1) * C + nn];
            hv.z = (_Float16)W[(long)(k0 + kq * 4 + 2) * C + nn];
            hv.w = (_Float16)W[(long)(k0 + kq * 4 + 3) * C + nn];
            *(f16x4*)&w_lds[nn * AST + kq * 4] = hv;
        }
        __syncthreads();

#pragma unroll
        for (int ks = 0; ks < KC; ks += 32) {
            f16x8 a0 = *(const f16x8*)&a_lds[(w * 32 + l16) * AST + ks + quad * 8];
            f16x8 a1 = *(const f16x8*)&a_lds[(w * 32 + 16 + l16) * AST + ks + quad * 8];
#pragma unroll
            for (int t = 0; t < NT; t++) {
                f16x8 b = *(const f16x8*)&w_lds[(t * 16 + l16) * AST + ks + quad * 8];
                acc[0][t] = __builtin_amdgcn_mfma_f32_16x16x32_f16(a0, b, acc[0][t], 0, 0, 0);
                acc[1][t] = __builtin_amdgcn_mfma_f32_16x16x32_f16(a1, b, acc[1][t], 0, 0, 0);
            }
        }
        __syncthreads();
    }

    // epilogue: C/D layout col=l16, row=quad*4+reg
#pragma unroll
    for (int sub = 0; sub < 2; sub++) {
        long rb = r0 + w * 32 + sub * 16 + quad * 4;
#pragma unroll
        for (int t = 0; t < NT; t++) {
            int c = t * 16 + l16;
#pragma unroll
            for (int rg = 0; rg < 4; rg++) {
                long row = rb + rg;
                if (row < n) {
                    __half hv = __float2half(acc[sub][t][rg]);
                    if (OUT_MODE == 0)
                        xp[row * 256 + ((c >> 1) << 2) + (c & 1) + set_off] = hv;
                    else
                        xp[row * (long)C + c] = hv;
                }
            }
        }
    }
}

// ---------------------------------------------------------------------------
// Fused attention coefficients for conv1 from packed fp16 xpc.
// ---------------------------------------------------------------------------
__global__ __launch_bounds__(256) void attn1_fused(const __half2* __restrict__ xpc,
                                                   const float* __restrict__ as_w, const float* __restrict__ ad_w,
                                                   float2* __restrict__ att_s, float2* __restrict__ att_d, int n) {
    int idx = blockIdx.x * 256 + threadIdx.x;
    if (idx >= n * 4) return;
    int v = idx >> 2, hh = idx & 3;
    const __half2* row = xpc + (long)v * 128 + hh * 32;   // 16 chunks x 2 half2
    const float* a1 = as_w + hh * 32;
    const float* a2 = ad_w + hh * 32;
    float sp1 = 0.f, sp2 = 0.f, sg1 = 0.f, sg2 = 0.f;
#pragma unroll
    for (int t = 0; t < 16; t++) {
        float2 fp = __half22float2(row[2 * t]);
        float2 fg = __half22float2(row[2 * t + 1]);
        float2 w1 = *(const float2*)(a1 + 2 * t);
        float2 w2 = *(const float2*)(a2 + 2 * t);
        sp1 += fp.x * w1.x + fp.y * w1.y;
        sp2 += fp.x * w2.x + fp.y * w2.y;
        sg1 += fg.x * w1.x + fg.y * w1.y;
        sg2 += fg.x * w2.x + fg.y * w2.y;
    }
    att_s[idx] = make_float2(sp1, sg1);
    att_d[idx] = make_float2(sp2, sg2);
}

// attention for conv2 (H=1, C=64), fp16 xp
__global__ __launch_bounds__(256) void attn2_kernel(const __half2* __restrict__ xp,
                                                    const float* __restrict__ as_w, const float* __restrict__ ad_w,
                                                    float* __restrict__ asrc, float* __restrict__ adst, int n) {
    int v = blockIdx.x * 256 + threadIdx.x;
    if (v >= n) return;
    const __half2* p = xp + (long)v * 32;
    float s1 = 0.f, s2 = 0.f;
#pragma unroll
    for (int c = 0; c < 32; c++) {
        float2 xv = __half22float2(p[c]);
        float2 w1 = *(const float2*)(as_w + 2 * c);
        float2 w2 = *(const float2*)(ad_w + 2 * c);
        s1 += xv.x * w1.x + xv.y * w1.y;
        s2 += xv.x * w2.x + xv.y * w2.y;
    }
    asrc[v] = s1;
    adst[v] = s2;
}

// ---------------------------------------------------------------------------
// Per-edge exp-weight precompute for conv1 (8 weights/edge, 32 B sequential).
// ---------------------------------------------------------------------------
__global__ __launch_bounds__(256) void w1prep(const int* __restrict__ csr, const int* __restrict__ dstv,
                                              const float4* __restrict__ att_s4, const float4* __restrict__ att_d4,
                                              float4* __restrict__ wb4) {
    int j = blockIdx.x * 256 + threadIdx.x;
    if (j >= ET) return;
    int s = csr[j], v = dstv[j];
    float4 s0 = att_s4[s * 2], s1 = att_s4[s * 2 + 1];
    float4 d0 = att_d4[v * 2], d1 = att_d4[v * 2 + 1];
    auto w = [](float e) { e = (e > 0.f) ? e : NEG * e; return __expf(e); };
    float4 w0, w1;
    w0.x = w(s0.x + d0.x); w0.y = w(s0.y + d0.y);
    w0.z = w(s0.z + d0.z); w0.w = w(s0.w + d0.w);
    w1.x = w(s1.x + d1.x); w1.y = w(s1.y + d1.y);
    w1.z = w(s1.z + d1.z); w1.w = w(s1.w + d1.w);
    wb4[j * 2]     = w0;
    wb4[j * 2 + 1] = w1;
}

// Per-edge exp-weight for conv2 (H=1): 4 B/edge.
__global__ __launch_bounds__(256) void w2prep(const int* __restrict__ csr, const int* __restrict__ dstv,
                                              const float* __restrict__ asrc, const float* __restrict__ adst,
                                              float* __restrict__ w2b) {
    int j = blockIdx.x * 256 + threadIdx.x;
    if (j >= ET) return;
    float e = asrc[csr[j]] + adst[dstv[j]];
    e = (e > 0.f) ? e : NEG * e;
    w2b[j] = __expf(e);
}

// ---------------------------------------------------------------------------
// Fused single-pass conv1 edge kernel. One wave per dst node; lane l carries
// channels {2l,2l+1} of both feature sets via ONE 8B gather from the packed
// fp16 layout. Predicated 8-wide chunks: tail edges are clamped duplicate
// gathers (L1 hits) with zeroed weights -> exact math, uniform 8 loads in
// flight. Output hbuf is fp16 (feeds GEMM2 directly).
// ---------------------------------------------------------------------------
__global__ __launch_bounds__(256) void conv1_edge_fused(const int* __restrict__ rs, const int* __restrict__ csr,
                                                        const uint2* __restrict__ xpc,
                                                        const float2* __restrict__ wb,
                                                        const float* __restrict__ bias,
                                                        __half* __restrict__ out) {
    int v = blockIdx.x * 4 + (threadIdx.x >> 6);
    if (v >= NN) return;
    int lane = threadIdx.x & 63;
    int e0 = rs[v], e1 = rs[v + 1];
    int c0 = lane * 2;
    int h0 = lane >> 4;                    // head = c0/32

    float ap0 = 0.f, ap1 = 0.f, ag0 = 0.f, ag1 = 0.f;
    float dp = 0.f, dg = 0.f;

    for (int j = e0; j < e1; j += 8) {
        int jc[8], s[8];
        float2 wv[8];
        uint2 r[8];
#pragma unroll
        for (int q = 0; q < 8; q++) { int jj = j + q; jc[q] = (jj < e1) ? jj : (e1 - 1); }
#pragma unroll
        for (int q = 0; q < 8; q++) s[q] = csr[jc[q]];
#pragma unroll
        for (int q = 0; q < 8; q++) wv[q] = wb[jc[q] * 4 + h0];
#pragma unroll
        for (int q = 0; q < 8; q++) r[q] = xpc[(long)s[q] * 64 + lane];
#pragma unroll
        for (int q = 0; q < 8; q++) {
            bool ok = (j + q) < e1;
            float wx = ok ? wv[q].x : 0.f;
            float wy = ok ? wv[q].y : 0.f;
            dp += wx; dg += wy;
            float2 fp = __half22float2(*(__half2*)&r[q].x);
            float2 fg = __half22float2(*(__half2*)&r[q].y);
            ap0 += wx * fp.x; ap1 += wx * fp.y;
            ag0 += wy * fg.x; ag1 += wy * fg.y;
        }
    }

    float ivp = 1.0f / dp, ivg = 1.0f / dg;
    float b0 = bias[c0], b1v = bias[c0 + 1];
    __half* o = out + (long)v * 256;
    o[c0]           = __float2half(fmaxf(ap0 * ivp + b0, 0.f));
    o[c0 + 1]       = __float2half(fmaxf(ap1 * ivp + b1v, 0.f));
    o[128 + c0]     = __float2half(fmaxf(ag0 * ivg + b0, 0.f));
    o[128 + c0 + 1] = __float2half(fmaxf(ag1 * ivg + b1v, 0.f));
}

// ---------------------------------------------------------------------------
// Single-pass conv2 edge kernel (H=1, C=64, fp16 xp), precomputed weights,
// predicated 8-wide chunks.
// ---------------------------------------------------------------------------
__global__ __launch_bounds__(256) void conv2_edge(const int* __restrict__ rs, const int* __restrict__ csr,
                                                  const __half* __restrict__ xp,
                                                  const float* __restrict__ w2b,
                                                  const float* __restrict__ bias,
                                                  float* __restrict__ out) {
    int v = blockIdx.x * 4 + (threadIdx.x >> 6);
    if (v >= NN) return;
    int lane = threadIdx.x & 63;
    int e0 = rs[v], e1 = rs[v + 1];

    float acc = 0.f, d = 0.f;
    for (int j = e0; j < e1; j += 8) {
        int jc[8], s[8];
        float w[8], x[8];
#pragma unroll
        for (int q = 0; q < 8; q++) { int jj = j + q; jc[q] = (jj < e1) ? jj : (e1 - 1); }
#pragma unroll
        for (int q = 0; q < 8; q++) s[q] = csr[jc[q]];
#pragma unroll
        for (int q = 0; q < 8; q++) w[q] = ((j + q) < e1) ? w2b[jc[q]] : 0.f;
#pragma unroll
        for (int q = 0; q < 8; q++) x[q] = __half2float(xp[(long)s[q] * 64 + lane]);
#pragma unroll
        for (int q = 0; q < 8; q++) { d += w[q]; acc += w[q] * x[q]; }
    }
    out[(long)v * 64 + lane] = acc / d + bias[lane];
}

// ---------------------------------------------------------------------------
// Launch
// ---------------------------------------------------------------------------
extern "C" void kernel_launch(void* const* d_in, const int* in_sizes, int n_in,
                              void* d_out, int out_size, void* d_ws, size_t ws_size,
                              hipStream_t stream) {
    const float* x_ppi = (const float*)d_in[0];
    const float* x_go  = (const float*)d_in[1];
    const int*   ei    = (const int*)d_in[2];
    const float* W1    = (const float*)d_in[3];
    const float* as1   = (const float*)d_in[4];
    const float* ad1   = (const float*)d_in[5];
    const float* b1    = (const float*)d_in[6];
    const float* W2    = (const float*)d_in[7];
    const float* as2   = (const float*)d_in[8];
    const float* ad2   = (const float*)d_in[9];
    const float* b2    = (const float*)d_in[10];
    float* out = (float*)d_out;

    char* ws = (char*)d_ws;
    size_t off = 0;
    auto alloc = [&](size_t bytes) -> void* {
        void* p = ws + off;
        off = (off + bytes + 255) & ~(size_t)255;
        return p;
    };
    int* deg     = (int*)alloc((size_t)NN * 4);
    int* rs      = (int*)alloc((size_t)(NN + 1) * 4);
    int* cur     = (int*)alloc((size_t)NN * 4);
    int* part    = (int*)alloc(512 * 4);
    int* csr     = (int*)alloc((size_t)ET * 4);
    int* dstv    = (int*)alloc((size_t)ET * 4);
    __half* xpc  = (__half*)alloc((size_t)NN * 256 * 2);   // packed {p0,p1,g0,g1} fp16
    __half* xp2  = (__half*)alloc((size_t)NN * 64 * 2);    // conv2 features fp16
    float2* atts = (float2*)alloc((size_t)NN * 4 * 8);
    float2* attd = (float2*)alloc((size_t)NN * 4 * 8);
    float* asr2  = (float*)alloc((size_t)NN * 4);
    float* ads2  = (float*)alloc((size_t)NN * 4);
    float* wb1   = (float*)alloc((size_t)ET * 32);         // 8 fp32 weights / edge
    float* w2b   = (float*)alloc((size_t)ET * 4);
    __half* hbuf = (__half*)alloc((size_t)NN * 256 * 2);   // conv1 output, fp16
    (void)ws_size; (void)in_sizes; (void)n_in; (void)out_size;

    const int NB = (NN + 255) / 256;        // 391
    const int EB = (ET + 255) / 256;        // 6641
    const int GB = (NN + 127) / 128;        // 782 (MFMA gemm blocks)

    // CSR build (shared by all three convs)
    hipMemsetAsync(deg, 0, (size_t)NN * 4, stream);
    k_count<<<EB, 256, 0, stream>>>(ei, deg);
    k_part<<<NB, 256, 0, stream>>>(deg, part);
    k_scanp<<<1, 512, 0, stream>>>(part, NB);
    k_scan<<<NB, 256, 0, stream>>>(deg, part, rs, cur);
    k_scatter<<<EB, 256, 0, stream>>>(ei, cur, csr, dstv);

    // layer 1: two MFMA GEMMs into packed fp16, fused attn, weight prep, edge conv
    gemm_mfma<128, 128, 0, true><<<GB, 256, 0, stream>>>(x_ppi, W1, xpc, NN, 0);
    gemm_mfma<128, 128, 0, true><<<GB, 256, 0, stream>>>(x_go, W1, xpc, NN, 2);
    attn1_fused<<<(NN * 4 + 255) / 256, 256, 0, stream>>>((const __half2*)xpc, as1, ad1, atts, attd, NN);
    w1prep<<<EB, 256, 0, stream>>>(csr, dstv, (const float4*)atts, (const float4*)attd, (float4*)wb1);
    conv1_edge_fused<<<NN / 4, 256, 0, stream>>>(rs, csr, (const uint2*)xpc, (const float2*)wb1, b1, hbuf);

    // layer 2
    gemm_mfma<256, 64, 1, false><<<GB, 256, 0, stream>>>(hbuf, W2, xp2, NN, 0);
    attn2_kernel<<<(NN + 255) / 256, 256, 0, stream>>>((const __half2*)xp2, as2, ad2, asr2, ads2, NN);
    w2prep<<<EB, 256, 0, stream>>>(csr, dstv, asr2, ads2, w2b);
    conv2_edge<<<NN / 4, 256, 0, stream>>>(rs, csr, xp2, w2b, b2, out);
}